// Round 1
// baseline (201.979 us; speedup 1.0000x reference)
//
#include <hip/hip_runtime.h>

#define BIG 1e8f
#define NROW 256
#define MCOL 256
#define DDIM 32

typedef _Float16 half2_t __attribute__((ext_vector_type(2)));

__device__ __forceinline__ half2_t pack2(float a, float b) {
    half2_t h;
    h[0] = (_Float16)a;
    h[1] = (_Float16)b;
    return h;
}

__device__ __forceinline__ float dot2acc(half2_t a, half2_t b, float c) {
#if __has_builtin(__builtin_amdgcn_fdot2)
    return __builtin_amdgcn_fdot2(a, b, c, false);
#else
    return c + (float)a[0] * (float)b[0] + (float)a[1] * (float)b[1];
#endif
}

// softmin_gamma1(a,b,c) = -log(e^-a + e^-b + e^-c), numerically stable.
__device__ __forceinline__ float softmin3(float a, float b, float c) {
    float mn = fminf(fminf(a, b), c);
    float s = __expf(mn - a) + __expf(mn - b) + __expf(mn - c);
    return mn - __logf(s);
}

// One block per batch. 128 threads; thread t owns D-matrix columns c0=2t+1, c1=2t+2.
// Staggered wavefront: at step tau, thread t processes row i = tau - t (1-based),
// computing cells (i,c0),(i,c1). Register exchange via shfl_up; LDS parity buffer
// for the single wave0->wave1 boundary; one barrier per step.
__global__ __launch_bounds__(128, 1) void sdtw_kernel(
    const float* __restrict__ x, const float* __restrict__ y,
    float* __restrict__ partial) {
    // x rows packed to f16, chunk cc holds dims [8cc,8cc+8) of row r at xh4[cc*256+r]
    // -> wavefront read is stride-16B across lanes: conflict-free ds_read_b128.
    __shared__ float4 xh4[4 * NROW];
    __shared__ float x2s[NROW];
    __shared__ float2 bnd[2];  // parity-indexed {u1,w1} of thread 63 for thread 64

    const int tid = threadIdx.x;  // 0..127
    const int b = blockIdx.x;
    const float* xb = x + (size_t)b * (NROW * DDIM);
    const float* yb = y + (size_t)b * (MCOL * DDIM);

    // ---- stage x (2 rows per thread) ----
#pragma unroll
    for (int rr = 0; rr < 2; rr++) {
        int r = tid + rr * 128;
        const float4* xr4 = (const float4*)(xb + r * DDIM);
        float s2 = 0.f;
        float4 outv[4];
#pragma unroll
        for (int cc = 0; cc < 4; cc++) {
            float4 f0 = xr4[2 * cc];
            float4 f1 = xr4[2 * cc + 1];
            s2 += f0.x * f0.x + f0.y * f0.y + f0.z * f0.z + f0.w * f0.w;
            s2 += f1.x * f1.x + f1.y * f1.y + f1.z * f1.z + f1.w * f1.w;
            union { float4 f4; half2_t h2[4]; } u;
            u.h2[0] = pack2(f0.x, f0.y);
            u.h2[1] = pack2(f0.z, f0.w);
            u.h2[2] = pack2(f1.x, f1.y);
            u.h2[3] = pack2(f1.z, f1.w);
            outv[cc] = u.f4;
        }
#pragma unroll
        for (int cc = 0; cc < 4; cc++) xh4[cc * NROW + r] = outv[cc];
        x2s[r] = s2;
    }

    // ---- y columns (2 per thread) into registers ----
    half2_t yA[16], yB[16];
    float y2a = 0.f, y2b = 0.f;
    {
        const float4* ya4 = (const float4*)(yb + (2 * tid) * DDIM);
        const float4* yb4 = (const float4*)(yb + (2 * tid + 1) * DDIM);
#pragma unroll
        for (int q = 0; q < 8; q++) {
            float4 f = ya4[q];
            y2a += f.x * f.x + f.y * f.y + f.z * f.z + f.w * f.w;
            yA[2 * q] = pack2(f.x, f.y);
            yA[2 * q + 1] = pack2(f.z, f.w);
        }
#pragma unroll
        for (int q = 0; q < 8; q++) {
            float4 f = yb4[q];
            y2b += f.x * f.x + f.y * f.y + f.z * f.z + f.w * f.w;
            yB[2 * q] = pack2(f.x, f.y);
            yB[2 * q + 1] = pack2(f.z, f.w);
        }
    }
    __syncthreads();

    // DP registers: at loop top, u0=D[i-1][c0], u1=D[i-1][c1], w1=D[i-2][c1].
    float u0 = BIG, u1 = BIG, w1 = BIG;
    const int lane = tid & 63;

    for (int tau = 1; tau <= NROW + 127; tau++) {
        int i = tau - tid;
        bool act = (i >= 1) && (i <= NROW);

        // unconditional clamped x-row load: off the serial softmin chain,
        // lets the scheduler issue it right after the barrier
        int r = i - 1;
        r = (r < 0) ? 0 : ((r > NROW - 1) ? NROW - 1 : r);
        union { float4 f4[4]; half2_t h2[16]; } xr;
#pragma unroll
        for (int cc = 0; cc < 4; cc++) xr.f4[cc] = xh4[cc * NROW + r];
        float xx = x2s[r];

        // neighbor exchange: L = D[i][c0-1], G = D[i-1][c0-1]
        float L = __shfl_up(u1, 1);
        float G = __shfl_up(w1, 1);
        if (lane == 0) {
            if (tid == 0) {
                L = BIG;                       // D[i][0]
                G = (i == 1) ? 0.f : BIG;      // D[i-1][0], D[0][0]=0
            } else {                           // tid == 64
                float2 bb = bnd[(tau - 1) & 1];
                L = bb.x;
                G = bb.y;
            }
        }

        if (act) {
            float dotA = 0.f, dotB = 0.f;
#pragma unroll
            for (int q = 0; q < 16; q++) {
                dotA = dot2acc(xr.h2[q], yA[q], dotA);
                dotB = dot2acc(xr.h2[q], yB[q], dotB);
            }
            float dA = fmaxf(xx + y2a - 2.f * dotA, 0.f);
            float dB = fmaxf(xx + y2b - 2.f * dotB, 0.f);
            float v0 = dA + softmin3(u0, L, G);        // up, left, diag
            float v1 = dB + softmin3(u1, v0, u0);      // up, left, diag
            w1 = u1;
            u1 = v1;
            u0 = v0;
        }
        if (tid == 63) bnd[tau & 1] = make_float2(u1, w1);
        __syncthreads();
    }

    if (tid == 127) partial[b] = u1;  // D[256][256]
}

__global__ void reduce_mean(const float* __restrict__ partial,
                            float* __restrict__ out, int B) {
    int t = threadIdx.x;
    float v = (t < B) ? partial[t] : 0.f;
#pragma unroll
    for (int off = 32; off >= 1; off >>= 1) v += __shfl_down(v, off);
    __shared__ float acc[4];
    if ((t & 63) == 0) acc[t >> 6] = v;
    __syncthreads();
    if (t == 0) out[0] = (acc[0] + acc[1] + acc[2] + acc[3]) / (float)B;
}

extern "C" void kernel_launch(void* const* d_in, const int* in_sizes, int n_in,
                              void* d_out, int out_size, void* d_ws, size_t ws_size,
                              hipStream_t stream) {
    const float* x = (const float*)d_in[0];
    const float* y = (const float*)d_in[1];
    float* out = (float*)d_out;
    float* partial = (float*)d_ws;

    int B = in_sizes[0] / (NROW * DDIM);  // 256

    sdtw_kernel<<<dim3(B), dim3(128), 0, stream>>>(x, y, partial);
    reduce_mean<<<dim3(1), dim3(256), 0, stream>>>(partial, out, B);
}

// Round 2
// 176.718 us; speedup vs baseline: 1.1429x; 1.1429x over previous
//
#include <hip/hip_runtime.h>

#define BIG 1e8f
#define LOG2E 1.44269504f
#define LN2 0.69314718f

typedef _Float16 half8 __attribute__((ext_vector_type(8)));
typedef _Float16 half4_t __attribute__((ext_vector_type(4)));
typedef float f32x4 __attribute__((ext_vector_type(4)));

__device__ __forceinline__ float exp2g(float x) {
#if __has_builtin(__builtin_amdgcn_exp2f)
    return __builtin_amdgcn_exp2f(x);
#else
    return exp2f(x);
#endif
}
__device__ __forceinline__ float log2g(float x) {
#if __has_builtin(__builtin_amdgcn_logf)
    return __builtin_amdgcn_logf(x);
#else
    return log2f(x);
#endif
}

// base-2 softmin3: -log2(2^-a + 2^-b + 2^-c), stable
__device__ __forceinline__ float sm3(float a, float b, float c) {
    float mn = fminf(fminf(a, b), c);
    return mn - log2g(exp2g(mn - a) + exp2g(mn - b) + exp2g(mn - c));
}
// base-2 softmin(pair, v) with precomputed pair (m = min, s = 2^(m-p)+2^(m-q))
__device__ __forceinline__ float smp(float m, float s, float v) {
    float mn = fminf(m, v);
    return mn - log2g(exp2g(mn - v) + s * exp2g(mn - m));
}

// Produce one 16-row stripe of the (log2e-scaled) distance matrix into the LDS
// ring band via MFMA.  Wave-wide; condition at call site must be wave-uniform.
__device__ __forceinline__ void produce_stripe(int s, int tid,
                                               const _Float16* xh,
                                               const float* x2s,
                                               const float* y2s,
                                               _Float16* band,
                                               const half8* yfrag) {
    const int rbase = s * 16;
    // A-frag: lane l holds x[rbase + (l&15)][(l>>4)*8 + j], j=0..7 (16B contig)
    const half8 a = *(const half8*)&xh[(rbase + (tid & 15)) * 32 + (tid >> 4) * 8];
    _Float16* bs = band + (s % 5) * 4096;
    float xr[4];
#pragma unroll
    for (int rq = 0; rq < 4; rq++) xr[rq] = x2s[rbase + (tid >> 4) * 4 + rq];
    const int col0 = tid & 15;
#pragma unroll
    for (int ci = 0; ci < 16; ci++) {
        f32x4 acc = {0.f, 0.f, 0.f, 0.f};
        acc = __builtin_amdgcn_mfma_f32_16x16x32_f16(a, yfrag[ci], acc, 0, 0, 0);
        const int col = ci * 16 + col0;
        const float yy = y2s[col];
#pragma unroll
        for (int rq = 0; rq < 4; rq++) {
            // C/D layout: col = lane&15, row = (lane>>4)*4 + reg
            float dv = fmaxf(xr[rq] + yy - 2.f * acc[rq], 0.f) * LOG2E;
            bs[((tid >> 4) * 4 + rq) * 256 + col] = (_Float16)dv;
        }
    }
}

// One block = one batch = ONE wave (64 threads).  Thread t owns 4 columns
// c = 4t+1..4t+4 (1-based).  Staggered wavefront, row i = tau - t; no barriers
// in the DP loop.  dist stripes are MFMA-produced into a 5-slot LDS ring,
// pipelined 5 stripes ahead of the wavefront.
__global__ __launch_bounds__(64, 1) void sdtw_kernel(
    const float* __restrict__ x, const float* __restrict__ y,
    float* __restrict__ out) {
    __shared__ __align__(16) _Float16 xh[256 * 32];       // 16 KB, row-major
    __shared__ float x2s[256];
    __shared__ float y2s[256];
    __shared__ __align__(16) _Float16 band[5 * 16 * 256]; // 40 KB ring

    const int tid = threadIdx.x;
    const int b = blockIdx.x;
    const float* xb = x + (size_t)b * 8192;
    const float* yb = y + (size_t)b * 8192;

    // ---- phase 0: stage x as f16 + row norms; y norms; y B-frags in regs ----
    for (int rr = 0; rr < 4; rr++) {
        const int r = tid + rr * 64;
        const float4* px = (const float4*)(xb + r * 32);
        union { _Float16 h[32]; half8 v[4]; } uc;
        float s2 = 0.f;
#pragma unroll
        for (int q = 0; q < 8; q++) {
            float4 f = px[q];
            s2 += f.x * f.x + f.y * f.y + f.z * f.z + f.w * f.w;
            uc.h[4 * q + 0] = (_Float16)f.x;
            uc.h[4 * q + 1] = (_Float16)f.y;
            uc.h[4 * q + 2] = (_Float16)f.z;
            uc.h[4 * q + 3] = (_Float16)f.w;
        }
        half8* dst = (half8*)&xh[r * 32];
#pragma unroll
        for (int q = 0; q < 4; q++) dst[q] = uc.v[q];
        x2s[r] = s2;

        const float4* py = (const float4*)(yb + r * 32);
        float t2 = 0.f;
#pragma unroll
        for (int q = 0; q < 8; q++) {
            float4 f = py[q];
            t2 += f.x * f.x + f.y * f.y + f.z * f.z + f.w * f.w;
        }
        y2s[r] = t2;
    }

    half8 yfrag[16];  // B-frag: lane l holds y[ci*16 + (l&15)][(l>>4)*8 + j]
#pragma unroll
    for (int ci = 0; ci < 16; ci++) {
        const float* yp = yb + (ci * 16 + (tid & 15)) * 32 + (tid >> 4) * 8;
        float4 f0 = *(const float4*)yp;
        float4 f1 = *(const float4*)(yp + 4);
        half8 v;
        v[0] = (_Float16)f0.x; v[1] = (_Float16)f0.y;
        v[2] = (_Float16)f0.z; v[3] = (_Float16)f0.w;
        v[4] = (_Float16)f1.x; v[5] = (_Float16)f1.y;
        v[6] = (_Float16)f1.z; v[7] = (_Float16)f1.w;
        yfrag[ci] = v;
    }
    __syncthreads();  // single wave: nearly free

    // ---- prologue: stripes 0..4 fill the ring ----
    for (int s = 0; s < 5; s++)
        produce_stripe(s, tid, xh, x2s, y2s, band, yfrag);
    __syncthreads();

    // ---- DP wavefront (base-2 scaled domain) ----
    // u0..u3 = Dhat[i-1][c0..c3], w3 = Dhat[i-2][c3]
    float u0 = BIG, u1 = BIG, u2 = BIG, u3 = BIG, w3 = BIG;

    for (int tau = 1; tau <= 319; tau++) {
        if ((tau & 15) == 0) {  // wave-uniform: produce stripe s at tau = 16s
            int s = tau >> 4;
            if (s >= 5 && s <= 15)
                produce_stripe(s, tid, xh, x2s, y2s, band, yfrag);
        }

        const int i = tau - tid;
        const bool act = (i >= 1) && (i <= 256);
        int r = i - 1;
        r = (r < 0) ? 0 : ((r > 255) ? 255 : r);
        const int slot = (r >> 4) % 5;
        half4_t dh = *(const half4_t*)&band[slot * 4096 + (r & 15) * 256 + tid * 4];
        const float d0 = (float)dh[0], d1 = (float)dh[1];
        const float d2 = (float)dh[2], d3 = (float)dh[3];

        float L = __shfl_up(u3, 1);  // Dhat[i][c0-1]
        float G = __shfl_up(w3, 1);  // Dhat[i-1][c0-1]
        if (tid == 0) {
            L = BIG;
            G = (i == 1) ? 0.f : BIG;
        }

        // off-chain pair precomputes
        const float mA = fminf(u1, u0), sA = exp2g(mA - u1) + exp2g(mA - u0);
        const float mB = fminf(u2, u1), sB = exp2g(mB - u2) + exp2g(mB - u1);
        const float mC = fminf(u3, u2), sC = exp2g(mC - u3) + exp2g(mC - u2);

        // serial chain: 4 softmins, ~1 exp+fma+log each
        const float v0 = d0 + sm3(u0, L, G);
        const float v1 = d1 + smp(mA, sA, v0);
        const float v2 = d2 + smp(mB, sB, v1);
        const float v3 = d3 + smp(mC, sC, v2);

        if (act) {
            w3 = u3;
            u0 = v0; u1 = v1; u2 = v2; u3 = v3;
        }
    }

    if (tid == 63) atomicAdd(out, u3 * (LN2 / 256.f));  // unscale + mean
}

extern "C" void kernel_launch(void* const* d_in, const int* in_sizes, int n_in,
                              void* d_out, int out_size, void* d_ws, size_t ws_size,
                              hipStream_t stream) {
    const float* x = (const float*)d_in[0];
    const float* y = (const float*)d_in[1];
    float* out = (float*)d_out;
    const int B = in_sizes[0] / (256 * 32);  // 256

    hipMemsetAsync(d_out, 0, sizeof(float), stream);
    sdtw_kernel<<<dim3(B), dim3(64), 0, stream>>>(x, y, out);
}